// Round 10
// baseline (407.094 us; speedup 1.0000x reference)
//
#include <hip/hip_runtime.h>

// LinearAttention bf16-MFMA pipeline. 256x256 GEMM, BK=64, 8-phase schedule.
// R19 = R18 core (best wall 406.6us, gemm8 K-loop byte-identical) + three
// boundary/locality moves (no core changes):
//  1) prep_kernel = cvt_x + cvt_wT + den-zero fused (3 dispatches -> 1).
//  2) QKV job remap: (pid,by) innermost per (b,bx). After the XCD chunk
//     swizzle, 12 consecutive same-XCD slots run ~concurrently on that XCD's
//     32 CUs and share ONE 512KB x-panel -> L2 serves 11/12 panel reads
//     (R18 ordering separated them by 64 slots -> full 3x re-fetch,
//     FETCH=229MB measured).
//  3) out-GEMM 4x4 supergroup decode: concurrent window = 4 Q-panels +
//     4 ctx-panels (4MB, L2-fit) instead of 32 distinct Q-panels.
// Floor model (R18 post-mortem): GEMM 343.6GF @ ~950TF ~= 362us + aux ~45us
// = 407us observed. At our shapes (K=1024, M/N=1024) the reference shape
// curve (m102) sits BELOW our effective rate -> schedule surgery exhausted;
// remaining levers are boundaries + panel L2 locality (this round).
//
// B=8, S=4096, D=1024, F=1024.
// out[b,f,s] = sum_g ctx[b,f,g] * Q[b,s,g]
//   ctx = (K^T V)/(den+eps);  Q = relu(x@Wq)+1
//   den[b,g] = sum_s K[b,s,g];  K = relu(x@Wk)+1;  V = x@Wv
// All GEMMs: C[M][N] = sum_k A[M][K] * Bt[N][K]  (NT, both row-major bf16).
//
// K-loop ledger: identical to R10/R14/R16/R18 — reg-pipelined 8 phases,
// 1 barrier/phase, vmcnt(2) publishes at ph3/ph7.

#define EPSF 1e-6f

constexpr int Bb = 8;
constexpr int Ss = 4096;
constexpr int Dd = 1024;
constexpr int Ff = 1024;

typedef __attribute__((ext_vector_type(8))) short   bf16x8;
typedef __attribute__((ext_vector_type(8))) unsigned short u16x8;
typedef __attribute__((ext_vector_type(4))) float   f32x4;

// explicit LDS (addrspace 3) pointer types
typedef __attribute__((address_space(3))) unsigned char lds_u8;
typedef __attribute__((address_space(3))) const bf16x8  lds_cvec;

static __device__ __forceinline__ unsigned short f2bf(float f) {
    union { float f; unsigned int u; } v; v.f = f;
    unsigned int r = (v.u + 0x7fffu + ((v.u >> 16) & 1u)) >> 16;
    return (unsigned short)r;
}
static __device__ __forceinline__ float bf2f(unsigned short u) {
    union { unsigned int u; float f; } v; v.u = ((unsigned int)u) << 16;
    return v.f;
}

static __device__ __forceinline__ void gld_lds16(const void* g, lds_u8* l) {
    __builtin_amdgcn_global_load_lds(
        (const __attribute__((address_space(1))) unsigned int*)g,
        (__attribute__((address_space(3))) unsigned int*)l,
        16, 0, 0);
}

// ---------------------------------------------------------------------------
// prep: blocks [0,32768) cvt x fp32->bf16; [32768,35840) transpose+cvt W;
// block 35840 zeroes den. (nx/4 = 8388608 = 32768*256 exactly.)
__global__ __launch_bounds__(256)
void prep_kernel(const float* __restrict__ x,
                 const float* __restrict__ Wq,
                 const float* __restrict__ Wk,
                 const float* __restrict__ Wv,
                 unsigned short* __restrict__ xb,
                 unsigned short* __restrict__ WT,
                 float* __restrict__ den)
{
    __shared__ float tile[32][33];
    const int bid = blockIdx.x;
    const int tid = threadIdx.x;
    if (bid < 32768) {
        const int i = bid * 256 + tid;
        float4 v = *(const float4*)&x[(size_t)i * 4];
        ushort4 o;
        o.x = f2bf(v.x); o.y = f2bf(v.y); o.z = f2bf(v.z); o.w = f2bf(v.w);
        *(ushort4*)&xb[(size_t)i * 4] = o;
    } else if (bid < 35840) {
        const int w = bid - 32768;
        const int z = w >> 10;                 // weight index (1024 blocks each)
        const int r = w & 1023;
        const int d0 = (r >> 5) * 32, f0 = (r & 31) * 32;
        const float* __restrict__ W = (z == 0) ? Wq : (z == 1 ? Wk : Wv);
        unsigned short* __restrict__ dst = WT + (size_t)z * Dd * Ff;
        const int c = tid & 31, r8 = tid >> 5;
#pragma unroll
        for (int p = 0; p < 4; ++p) {
            int rr = p * 8 + r8;
            tile[rr][c] = W[(size_t)(d0 + rr) * Ff + f0 + c];
        }
        __syncthreads();
#pragma unroll
        for (int p = 0; p < 4; ++p) {
            int rr = p * 8 + r8;
            dst[(size_t)(f0 + rr) * Dd + d0 + c] = f2bf(tile[c][rr]);
        }
    } else {
        for (int i = tid; i < Bb * Ff; i += 256) den[i] = 0.f;
    }
}

// ctx[b][f][g] = (p[2b] + p[2b+1]) / (den[b][g] + eps)   (bf16 partials)
__global__ void add_ctx_kernel(const unsigned short* __restrict__ p,
                               unsigned short* __restrict__ c,
                               const float* __restrict__ den)
{
    const int b = blockIdx.y;
    const size_t i8 = ((size_t)blockIdx.x * 256 + threadIdx.x) * 8;
    const int g0 = (int)(i8 & (size_t)(Ff - 1));
    const u16x8 a0 = *(const u16x8*)(p + (size_t)(2 * b) * Ff * Ff + i8);
    const u16x8 a1 = *(const u16x8*)(p + (size_t)(2 * b + 1) * Ff * Ff + i8);
    const float4 d0 = *(const float4*)&den[(size_t)b * Ff + g0];
    const float4 d1 = *(const float4*)&den[(size_t)b * Ff + g0 + 4];
    const float dv[8] = {d0.x, d0.y, d0.z, d0.w, d1.x, d1.y, d1.z, d1.w};
    u16x8 o;
#pragma unroll
    for (int j = 0; j < 8; ++j)
        o[j] = f2bf((bf2f(a0[j]) + bf2f(a1[j])) * (1.f / (dv[j] + EPSF)));
    *(u16x8*)(c + (size_t)b * Ff * Ff + i8) = o;
}

// ---------------------------------------------------------------------------
// 256x256 NT bf16 MFMA GEMM, 512 threads, 8 waves (2M x 4N), BK=64, 8-phase,
// register-pipelined (frags read one phase ahead), 1 barrier/phase.
// LDS: buf0.A@0 buf0.B@32K buf1.A@64K buf1.B@96K; each [256 rows][128B],
// 16B-chunk XOR-swizzle key=(row&7). MFMA swapped operands (C^T frags).
// MODE 0: generic (z,by,bx from grid shape; SPLITK2 honored).
// MODE 1: QKV merged; decode (pid,by) innermost per (b,bx) for x-panel L2
//         reuse: pid=j%3, by=(j/3)%4, bx=(j/12)%16, b=j/192.
//         pid0=Q (A=xb, B=Wq, C=Qb[S][F]); pid1=K (relu1+den atomics,
//         C=KbT[F][S]); pid2=V (plain, C=VbT[F][S]).
// MODE 2: out-GEMM; 4x4 supergroup decode: b=j/64, sg=(j%64)/16, i=j%16,
//         bx=sg*4+(i&3), by=i>>2.
template<int ACT, int SCALE, int OUT_BF16, int SPLITK2, int DENACC, int MODE>
__global__ __launch_bounds__(512, 2)
void gemm8(const unsigned short* __restrict__ A,
           const unsigned short* __restrict__ Bt,
           void* __restrict__ Cout,
           const float* __restrict__ den,
           float* __restrict__ denw,
           int lda, int ldb, int ldc, int Kdim,
           size_t strideA, size_t strideB, size_t strideC)
{
    __shared__ __align__(16) unsigned char smem_[131072];
    lds_u8* const smem = (lds_u8*)smem_;

    // ---- XCD-aware bijective block swizzle (total blocks % 8 == 0 always)
    const int gx = gridDim.x, gxy = gx * gridDim.y;
    int flat = blockIdx.z * gxy + blockIdx.y * gx + blockIdx.x;
    const int nwg = gxy * gridDim.z;
    const int cpx = nwg >> 3;
    flat = (flat & 7) * cpx + (flat >> 3);

    int pid = 0, zb = 0, bm, bn, ldcr;
    size_t coff, koff = 0;
    bool actv, dacc;
    const unsigned short* __restrict__ Ag;
    const unsigned short* __restrict__ Bg;

    if (MODE == 1) {
        // (pid,by) innermost per (b,bx): 12 consecutive slots share x-panel
        pid = flat % 3;
        int q = flat / 3;
        const int byq = q & 3;  q >>= 2;
        const int bxq = q & 15; zb = q >> 4;
        if (pid == 0) {          // Q: C[S][F] = relu1(xb @ Wq)
            Ag = Bt + (size_t)zb * Ss * Dd;      // xb slab (A-side, M=S)
            Bg = A;                              // Wq slice
            bm = bxq * 256; bn = byq * 256;
            ldcr = Ff;
            coff = (size_t)zb * Ss * Ff;
            actv = true;  dacc = false;
        } else {                 // K/V: C[F][S]
            Ag = A + (size_t)pid * Dd * Ff;      // Wk (pid1) / Wv (pid2)
            Bg = Bt + (size_t)zb * Ss * Dd;
            bm = byq * 256; bn = bxq * 256;
            ldcr = Ss;
            coff = ((size_t)pid * Bb + zb) * ((size_t)Ff * Ss);
            actv = (pid == 1); dacc = (pid == 1);
        }
    } else if (MODE == 2) {
        // out: 4x4 supergroup for Q/ctx panel L2 locality
        zb = flat >> 6;
        const int r = flat & 63;
        const int sg = r >> 4, i = r & 15;
        const int bxq = sg * 4 + (i & 3), byq = i >> 2;
        Ag = A + strideA * zb;
        Bg = Bt + strideB * zb;
        bm = byq * 256; bn = bxq * 256;
        ldcr = ldc;
        coff = strideC * (size_t)zb;
        actv = false; dacc = false;
    } else {
        const int z = flat / gxy;
        const int rem = flat - z * gxy;
        const int by = rem / gx;
        const int bx = rem - by * gx;
        zb   = SPLITK2 ? (z >> 1) : z;
        koff = SPLITK2 ? (size_t)((z & 1) * Kdim) : 0;
        Ag = A + strideA * zb + koff;
        Bg = Bt + strideB * zb + koff;
        bm = by * 256; bn = bx * 256;
        ldcr = ldc;
        coff = strideC * (size_t)z;
        actv = ACT; dacc = DENACC;
    }
    const float* __restrict__ denb = SCALE ? (den + (size_t)zb * Ff) : nullptr;

    const int tid  = threadIdx.x;
    const int wv   = tid >> 6, lane = tid & 63;
    const int wm   = wv >> 2, wn = wv & 3;        // 2 x 4 wave grid
    const int lm   = lane & 15;
    const int kg16 = (lane >> 4) << 4;            // k-group byte offset
    const int swz  = (lm & 7) << 4;               // read-side XOR key (row&7)
    const int kbs  = (((tid & 7) ^ ((tid >> 3) & 7)) << 4);  // stage src chunk
    const int srow = tid >> 3;                    // stage row within 64-row q-block

    f32x4 acc[8][4];
#pragma unroll
    for (int i = 0; i < 8; ++i)
#pragma unroll
        for (int j = 0; j < 4; ++j) acc[i][j] = (f32x4){0.f, 0.f, 0.f, 0.f};

    lds_u8* const A0 = smem;
    lds_u8* const B0 = smem + 32768;
    lds_u8* const A1 = smem + 65536;
    lds_u8* const B1 = smem + 98304;

    // stage one half-tile (16KB, 2 gld_lds16/thread) of K-tile ts.
    // m: 0=A 1=B; buf: 0/1; h: 0=rows0-127 1=rows128-255.
    auto STAGE = [&](int ts, int m, int buf, int h) {
        const unsigned short* gb = m ? Bg : Ag;
        const int ld = m ? ldb : lda;
        const int off0 = m ? bn : bm;
        lds_u8* lb = smem + buf * 65536 + m * 32768 + h * 16384 + wv * 1024;
#pragma unroll
        for (int q = 0; q < 2; ++q) {
            int row = h * 128 + q * 64 + srow;
            const unsigned char* g =
                (const unsigned char*)(gb + (size_t)(off0 + row) * ld + ts * 64) + kbs;
            gld_lds16(g, lb + q * 8192);
        }
    };
    auto LDA4 = [&](bf16x8* dst, int fmb, int kk, lds_u8* Ab) {
#pragma unroll
        for (int f = 0; f < 4; ++f) {
            int r = wm * 128 + (fmb + f) * 16 + lm;
            dst[f] = *(lds_cvec*)(Ab + r * 128 + ((kk * 64 + kg16) ^ swz));
        }
    };
    auto LDB4 = [&](bf16x8* dst, int kk, lds_u8* Bb) {
#pragma unroll
        for (int f = 0; f < 4; ++f) {
            int c = wn * 64 + f * 16 + lm;
            dst[f] = *(lds_cvec*)(Bb + c * 128 + ((kk * 64 + kg16) ^ swz));
        }
    };

    // swapped operands: D frag = C^T block (rows=N, cols=M)
#define MM16(a4, b4, mo)                                                        \
    do {                                                                        \
        __builtin_amdgcn_s_setprio(1);                                          \
        _Pragma("unroll")                                                       \
        for (int fm = 0; fm < 4; ++fm)                                          \
            _Pragma("unroll")                                                   \
            for (int fn = 0; fn < 4; ++fn)                                      \
                acc[(mo) + fm][fn] = __builtin_amdgcn_mfma_f32_16x16x32_bf16(   \
                    (b4)[fn], (a4)[fm], acc[(mo) + fm][fn], 0, 0, 0);           \
        __builtin_amdgcn_s_setprio(0);                                          \
    } while (0)

    // phase tail: drain own ds_reads, pin so nothing crosses, then the single
    // per-phase barrier. PHEND_VM2 also drains vmem to 2 outstanding
    // (buffer publish, per R10 ledger).
#define PHEND()                                                     \
    do {                                                            \
        asm volatile("s_waitcnt lgkmcnt(0)");                       \
        __builtin_amdgcn_sched_barrier(0);                          \
        __builtin_amdgcn_s_barrier();                               \
    } while (0)
#define PHEND_VM2()                                                 \
    do {                                                            \
        asm volatile("s_waitcnt vmcnt(2) lgkmcnt(0)");              \
        __builtin_amdgcn_sched_barrier(0);                          \
        __builtin_amdgcn_s_barrier();                               \
    } while (0)

    const int NT = Kdim >> 6;   // K-tiles of 64 (even, >= 8 here)
    const int NI = NT >> 1;

    // prologue: t0 {Bl,Bh,Al,Ah} -> buf0, t1 {Bl,Bh} -> buf1  (12 loads)
    STAGE(0, 1, 0, 0); STAGE(0, 1, 0, 1);
    STAGE(0, 0, 0, 0); STAGE(0, 0, 0, 1);
    STAGE(1, 1, 1, 0); STAGE(1, 1, 1, 1);
    asm volatile("s_waitcnt vmcnt(4)");      // t0 fully landed
    __builtin_amdgcn_s_barrier();

    bf16x8 a03[4], a47[4], b0[4], b1[4];
    // pre-read ph1 frags (tile 0, kk0, buf0)
    LDB4(b0, 0, B0); LDA4(a03, 0, 0, A0);

    for (int i = 0; i < NI; ++i) {
        const int t = 2 * i;
        const int t1s = t + 1;                       // always < NT
        const int t2s = (t + 2 < NT) ? t + 2 : NT - 1;
        const int t3s = (t + 3 < NT) ? t + 3 : NT - 1;

        // ph1
        STAGE(t1s, 0, 1, 0);
        LDA4(a47, 4, 0, A0);
        MM16(a03, b0, 0);
        PHEND();
        // ph2
        STAGE(t1s, 0, 1, 1);
        LDA4(a03, 0, 1, A0); LDB4(b1, 1, B0);
        MM16(a47, b0, 4);
        PHEND();
        // ph3  (publishes buf1 = tile t+1)
        STAGE(t2s, 1, 0, 0);
        LDA4(a47, 4, 1, A0);
        MM16(a03, b1, 0);
        PHEND_VM2();
        // ph4
        STAGE(t2s, 1, 0, 1);
        LDA4(a03, 0, 0, A1); LDB4(b0, 0, B1);
        MM16(a47, b1, 4);
        PHEND();
        // ph5
        STAGE(t2s, 0, 0, 0);
        LDA4(a47, 4, 0, A1);
        MM16(a03, b0, 0);
        PHEND();
        // ph6
        STAGE(t2s, 0, 0, 1);
        LDA4(a03, 0, 1, A1); LDB4(b1, 1, B1);
        MM16(a47, b0, 4);
        PHEND();
        // ph7  (publishes buf0 = tile t+2)
        STAGE(t3s, 1, 1, 0);
        LDA4(a47, 4, 1, A1);
        MM16(a03, b1, 0);
        PHEND_VM2();
        // ph8
        STAGE(t3s, 1, 1, 1);
        LDA4(a03, 0, 0, A0); LDB4(b0, 0, B0);   // next tile's ph1 frags
        MM16(a47, b1, 4);
        PHEND();
    }

    asm volatile("s_waitcnt vmcnt(0)");

    // ---- epilogue (swapped layout): frag (fm,fn):
    // row m = bm + wm*128 + fm*16 + lm ; cols n = bn + wn*64 + fn*16 + (lane>>4)*4
    const int hi4 = (lane >> 4) * 4;
#pragma unroll
    for (int fm = 0; fm < 8; ++fm) {
        const int gr = bm + wm * 128 + fm * 16 + lm;
        float rowsum = 0.f;
#pragma unroll
        for (int fn = 0; fn < 4; ++fn) {
            const int gcn = bn + wn * 64 + fn * 16 + hi4;
            f32x4 v = acc[fm][fn];
            if (actv) {
#pragma unroll
                for (int e = 0; e < 4; ++e) v[e] = fmaxf(v[e], 0.f) + 1.f;
            }
            if (dacc) rowsum += v[0] + v[1] + v[2] + v[3];
            if (SCALE) {
                float4 d4 = *(const float4*)&denb[gcn];
                v[0] *= 1.f / (d4.x + EPSF);
                v[1] *= 1.f / (d4.y + EPSF);
                v[2] *= 1.f / (d4.z + EPSF);
                v[3] *= 1.f / (d4.w + EPSF);
            }
            if (OUT_BF16) {
                ushort4 o;
                o.x = f2bf(v[0]); o.y = f2bf(v[1]); o.z = f2bf(v[2]); o.w = f2bf(v[3]);
                *(ushort4*)((unsigned short*)Cout + coff + (size_t)gr * ldcr + gcn) = o;
            } else {
                *(float4*)((float*)Cout + coff + (size_t)gr * ldcr + gcn) =
                    *(float4*)&v;
            }
        }
        if (dacc) {
            // lanes {lm, lm+16, lm+32, lm+48} share gr; reduce across them
            rowsum += __shfl_xor(rowsum, 16, 64);
            rowsum += __shfl_xor(rowsum, 32, 64);
            if (lane < 16) atomicAdd(denw + (size_t)zb * Ff + gr, rowsum);
        }
    }
#undef MM16
#undef PHEND
#undef PHEND_VM2
}

// ---------------------------------------------------------------------------
extern "C" void kernel_launch(void* const* d_in, const int* in_sizes, int n_in,
                              void* d_out, int out_size, void* d_ws, size_t ws_size,
                              hipStream_t stream)
{
    (void)in_sizes; (void)n_in; (void)out_size;
    const float* x  = (const float*)d_in[0];
    const float* Wq = (const float*)d_in[1];
    const float* Wk = (const float*)d_in[2];
    const float* Wv = (const float*)d_in[3];
    float* out = (float*)d_out;

    const size_t nx   = (size_t)Bb * Ss * Dd;
    const size_t nW   = (size_t)3 * Dd * Ff;
    const size_t nQKV = (size_t)Bb * Ss * Ff;
    const size_t nCtx = (size_t)Bb * Ff * Ff;
    const size_t nP   = (size_t)16 * Ff * Ff;   // split-K partials (bf16)

    unsigned short* xb   = (unsigned short*)d_ws;          // [B][S][D]
    unsigned short* WT   = xb + nx;                        // [3][F][D] (Wq,Wk,Wv)
    unsigned short* Qb   = WT + nW;                        // [B][S][F] (relu1, unscaled)
    unsigned short* KbT  = Qb + nQKV;                      // [B][F][S] (= Qb + 1*B*S*F)
    unsigned short* VbT  = KbT + nQKV;                     // [B][F][S] (= Qb + 2*B*S*F)
    unsigned short* ctxb = VbT + nQKV;                     // [B][F][F] (den-scaled)
    float* den = (float*)(ctxb + nCtx);                    // [B][F]
    unsigned short* pctx = (unsigned short*)(den + (size_t)Bb * Ff); // [16][F][F]

    const size_t need_split =
        ((nx + nW + 3 * nQKV + nCtx + nP) * 2 + (size_t)Bb * Ff * 4);
    const bool do_split = ws_size >= need_split;

    // prep: cvt x, transpose+cvt weights, zero den (one dispatch)
    prep_kernel<<<dim3(35841), 256, 0, stream>>>(x, Wq, Wk, Wv, xb, WT, den);

    // Merged Q+K+V projections (MODE=1), (pid,by)-innermost job order.
    //  pid0 -> Qb[S][F] (relu1); pid1 -> KbT[F][S] (relu1 + den atomics);
    //  pid2 -> VbT[F][S] (plain). A=WT base, Bt=xb, Cout=Qb.
    gemm8<0, 0, 1, 0, 0, 1><<<dim3(Ss / 256, Ff / 256, 3 * Bb), 512, 0, stream>>>(
        WT, xb, Qb, nullptr, den,
        Dd, Dd, 0, Dd, 0, 0, 0);

    // ctx[f][g] = (K^T V)/(den[g]+eps)
    if (do_split) {
        // split-K=2 partials (unscaled), then add+scale
        gemm8<0, 0, 1, 1, 0, 0><<<dim3(Ff / 256, Ff / 256, 2 * Bb), 512, 0, stream>>>(
            KbT, VbT, pctx, nullptr, nullptr,
            Ss, Ss, Ff, Ss / 2, (size_t)Ff * Ss, (size_t)Ff * Ss, (size_t)Ff * Ff);
        add_ctx_kernel<<<dim3(Ff * Ff / 8 / 256, Bb), 256, 0, stream>>>(pctx, ctxb, den);
    } else {
        // non-split: scale in GEMM epilogue (den complete after projections)
        gemm8<0, 1, 1, 0, 0, 0><<<dim3(Ff / 256, Ff / 256, Bb), 512, 0, stream>>>(
            KbT, VbT, ctxb, den, nullptr,
            Ss, Ss, Ff, Ss, (size_t)Ff * Ss, (size_t)Ff * Ss, (size_t)Ff * Ff);
    }

    // out[f][s] = ctx @ Q^T (fp32 out), MODE=2 (4x4 supergroup decode)
    gemm8<0, 0, 0, 0, 0, 2><<<dim3(Ss / 256, Ff / 256, Bb), 512, 0, stream>>>(
        ctxb, Qb, out, nullptr, nullptr,
        Ff, Ff, Ss, Ff, (size_t)Ff * Ff, (size_t)Ss * Ff, (size_t)Ff * Ss);
}